// Round 6
// baseline (191.200 us; speedup 1.0000x reference)
//
#include <hip/hip_runtime.h>
#include <hip/hip_bf16.h>
#include <math.h>

#define BB 64
#define SS 512
#define DD 1024
#define LL 9
#define NCHUNK 32

// update_dpp add: v += dpp_move(v, ctrl), inactive/invalid source lanes add 0
#define DPP_ADD(v, ctrl)                                                     \
  v += __int_as_float(__builtin_amdgcn_update_dpp(                           \
      0, __float_as_int(v), ctrl, 0xF, 0xF, false))
// full-wave sum -> lane 63: row_shr 1,2,4,8 then row_bcast15 (0x142),
// row_bcast31 (0x143)
#define WAVE_RED63(v)                                                        \
  do {                                                                       \
    DPP_ADD(v, 0x111);                                                       \
    DPP_ADD(v, 0x112);                                                       \
    DPP_ADD(v, 0x114);                                                       \
    DPP_ADD(v, 0x118);                                                       \
    DPP_ADD(v, 0x142);                                                       \
    DPP_ADD(v, 0x143);                                                       \
  } while (0)

template <int R>
__device__ inline float swz(float x) {
  return __int_as_float(
      __builtin_amdgcn_ds_swizzle(__float_as_int(x), (R << 10) | 0x1F));
}

// ---------------- Fused GEMM + chunk-scan kernel.
// 512 blocks x 256 threads; block = 64 rows = 4 chunks of one batch.
// GEMM phase: each wave owns 16 CONSECUTIVE rows, processed as 8 windows of
// 2 adjacent rows. Whole wave covers one row 64-way in k: lane holds
// k in {i*256 + 4*lane .. +3}, i=0..3 -> every global load is 1 KB
// contiguous; a window streams 8 KB contiguous; W tile read from LDS as
// ds_read_b128 (reused across the 2 rows). Row sums via 6-stage DPP
// reduce into lane 63, which stores 18 outputs (global + LDS Lg).
// Phase 2: wave 0 runs 4 transfer-matrix chunks from Lg; wave 1 does the
// block's numerator partial.
__global__ __launch_bounds__(256, 2) void fused_kernel(
    const float* __restrict__ in, const float* __restrict__ W,
    const float* __restrict__ bias, const int* __restrict__ targets,
    const int* __restrict__ seqlen, const float* __restrict__ trans,
    float* __restrict__ logits, float* __restrict__ mats,
    float* __restrict__ scales, float* __restrict__ numblk,
    unsigned* __restrict__ counter) {
  __shared__ float Wt[LL][DD];  // 36 KB, [l][k]
  __shared__ float Lg[64][LL];  // this block's logits rows
  int tid = threadIdx.x;
  int bid = blockIdx.x;
  if (bid == 0 && tid == 0) *counter = 0u;  // for combine's finisher

  for (int i = tid; i < DD * LL; i += 256) {
    int k = i / LL, l = i - k * LL;  // W row-major [k][l]
    Wt[l][k] = W[i];
  }
  __syncthreads();

  int lane = tid & 63;
  int wave = tid >> 6;

  float bv[LL];
#pragma unroll
  for (int l = 0; l < LL; ++l) bv[l] = bias[l];

  int rbase = bid * 64 + wave * 16;  // wave's 16 consecutive rows

  // a[j]: j = row2*4 + i  (row2 in {0,1}, i = k-chunk 0..3)
  float4 a[8], an[8];
  {
    const float* src = in + (size_t)rbase * DD + lane * 4;
#pragma unroll
    for (int j = 0; j < 8; ++j)
      a[j] = *reinterpret_cast<const float4*>(src + (size_t)(j >> 2) * DD +
                                              (j & 3) * 256);
  }

  for (int t = 0; t < 8; ++t) {
    int r = rbase + 2 * t;
    if (t < 7) {
      const float* src = in + (size_t)(r + 2) * DD + lane * 4;
#pragma unroll
      for (int j = 0; j < 8; ++j)
        an[j] = *reinterpret_cast<const float4*>(src + (size_t)(j >> 2) * DD +
                                                 (j & 3) * 256);
    }
    float acc0[LL], acc1[LL];
#pragma unroll
    for (int l = 0; l < LL; ++l) { acc0[l] = 0.f; acc1[l] = 0.f; }

#pragma unroll
    for (int i = 0; i < 4; ++i) {
      float4 w4[LL];
#pragma unroll
      for (int l = 0; l < LL; ++l)
        w4[l] = *reinterpret_cast<const float4*>(&Wt[l][i * 256 + lane * 4]);
      float4 x0 = a[i];
      float4 x1 = a[4 + i];
#pragma unroll
      for (int l = 0; l < LL; ++l) {
        acc0[l] += x0.x * w4[l].x + x0.y * w4[l].y + x0.z * w4[l].z +
                   x0.w * w4[l].w;
        acc1[l] += x1.x * w4[l].x + x1.y * w4[l].y + x1.z * w4[l].z +
                   x1.w * w4[l].w;
      }
    }

#pragma unroll
    for (int l = 0; l < LL; ++l) {
      WAVE_RED63(acc0[l]);
      WAVE_RED63(acc1[l]);
    }
    if (lane == 63) {
      int lr = r - bid * 64;
      float* g0 = logits + (size_t)r * LL;
#pragma unroll
      for (int l = 0; l < LL; ++l) {
        float v0 = acc0[l] + bv[l];
        float v1 = acc1[l] + bv[l];
        g0[l] = v0;
        g0[LL + l] = v1;
        Lg[lr][l] = v0;
        Lg[lr + 1][l] = v1;
      }
    }
    if (t < 7) {
#pragma unroll
      for (int j = 0; j < 8; ++j) a[j] = an[j];
    }
  }
  __syncthreads();

  int b = bid >> 3;
  int base = (bid & 7) * 64;  // block's first in-batch timestep
  int len = seqlen[b];

  if (wave == 0) {
    // ---- 4 transfer-matrix chunks, data-parallel across 16-lane groups
    int j = lane & 15;
    int g = lane >> 4;
    int kk = (bid & 7) * 4 + g;  // chunk index in batch, 0..31
    int gid = b * NCHUNK + kk;

    float Mx[81];
#pragma unroll
    for (int i = 0; i < 81; ++i) Mx[i] = __expf(trans[i]);

    float T[LL];
#pragma unroll
    for (int c = 0; c < LL; ++c) T[c] = (j == c) ? 1.f : 0.f;
    float Cl = 0.f;

    int tstart = (kk == 0) ? 1 : kk * 16;
    int tend = kk * 16 + 16;

    float e[LL];
#pragma unroll
    for (int c = 0; c < LL; ++c) e[c] = Lg[tstart - base][c];

    for (int t = tstart; t < tend; ++t) {
      float Ex[LL];
#pragma unroll
      for (int c = 0; c < LL; ++c) Ex[c] = __expf(e[c]);
      if (t + 1 < tend) {
#pragma unroll
        for (int c = 0; c < LL; ++c) e[c] = Lg[t + 1 - base][c];
      }
      bool active = (t < len);
      float nT[LL];
#pragma unroll
      for (int c = 0; c < LL; ++c) {
        float s = 0.f;
#pragma unroll
        for (int m = 0; m < LL; ++m) s += T[m] * Mx[m * LL + c];
        nT[c] = s * Ex[c];
      }
#pragma unroll
      for (int c = 0; c < LL; ++c) T[c] = active ? nT[c] : T[c];

      if (((t - tstart) & 7) == 7) {
        float m = T[0];
#pragma unroll
        for (int c = 1; c < LL; ++c) m = fmaxf(m, T[c]);
        m = fmaxf(m, swz<1>(m));
        m = fmaxf(m, swz<2>(m));
        m = fmaxf(m, swz<4>(m));
        m = fmaxf(m, swz<8>(m));
        float inv = 1.f / m;
#pragma unroll
        for (int c = 0; c < LL; ++c) T[c] *= inv;
        Cl += __logf(m);
      }
    }
    {
      float m = T[0];
#pragma unroll
      for (int c = 1; c < LL; ++c) m = fmaxf(m, T[c]);
      m = fmaxf(m, swz<1>(m));
      m = fmaxf(m, swz<2>(m));
      m = fmaxf(m, swz<4>(m));
      m = fmaxf(m, swz<8>(m));
      float inv = 1.f / m;
#pragma unroll
      for (int c = 0; c < LL; ++c) T[c] *= inv;
      Cl += __logf(m);
    }

    float* Mg = mats + (size_t)gid * 256;
#pragma unroll
    for (int c = 0; c < 16; ++c)
      Mg[c * 16 + (j ^ c)] = (c < LL) ? T[c] : 0.f;
    if (j == 0) scales[gid] = Cl;
  } else if (wave == 1) {
    // ---- numerator partial for this block's 64 timesteps
    int t = base + lane;
    float np = 0.f;
    const int* tb = targets + (size_t)b * SS;
    if (t >= 1 && t < len) {
      int tg = tb[t];
      np = Lg[lane][tg] + trans[tb[t - 1] * LL + tg];
    }
    np += __shfl_xor(np, 1, 64);
    np += __shfl_xor(np, 2, 64);
    np += __shfl_xor(np, 4, 64);
    np += __shfl_xor(np, 8, 64);
    np += __shfl_xor(np, 16, 64);
    np += __shfl_xor(np, 32, 64);
    if (lane == 0) numblk[bid] = np;
  }
}

// ---------------- Combine: per-batch matvec chain over 32 chunk matrices
// (tree-associated, renorm every 4 chunks) + deterministic final reduce.
__global__ __launch_bounds__(64) void crf_combine_kernel(
    const float* __restrict__ logits, const int* __restrict__ targets,
    const float* __restrict__ mats, const float* __restrict__ scales,
    const float* __restrict__ numblk, float* __restrict__ partials,
    unsigned* __restrict__ counter, float* __restrict__ out_val) {
  int lane = threadIdx.x;
  int j = lane & 15;
  int b = blockIdx.x;
  const float* lb = logits + (size_t)b * SS * LL;
  const float* Mb = mats + (size_t)b * NCHUNK * 256;

  // scales (32 lanes) minus numerator block partials (8 lanes), fixed order
  float extra = 0.f;
  if (lane < NCHUNK) extra = scales[b * NCHUNK + lane];
  else if (lane < NCHUNK + 8) extra = -numblk[b * 8 + (lane - NCHUNK)];
  extra += __shfl_xor(extra, 1, 64);
  extra += __shfl_xor(extra, 2, 64);
  extra += __shfl_xor(extra, 4, 64);
  extra += __shfl_xor(extra, 8, 64);
  extra += __shfl_xor(extra, 16, 64);
  extra += __shfl_xor(extra, 32, 64);
  float emit0 = lb[targets[(size_t)b * SS]];  // t=0 numerator term

  float alpha = (j < LL) ? __expf(lb[j]) : 0.f;
  float C = 0.f;

  float4 c0 = *reinterpret_cast<const float4*>(Mb + j * 16 + 0);
  float4 c1 = *reinterpret_cast<const float4*>(Mb + j * 16 + 4);
  float4 c2 = *reinterpret_cast<const float4*>(Mb + j * 16 + 8);
  float4 c3 = *reinterpret_cast<const float4*>(Mb + j * 16 + 12);

  for (int k = 0; k < NCHUNK; ++k) {
    float4 n0, n1, n2, n3;
    if (k + 1 < NCHUNK) {
      const float* Mn = Mb + (size_t)(k + 1) * 256 + j * 16;
      n0 = *reinterpret_cast<const float4*>(Mn + 0);
      n1 = *reinterpret_cast<const float4*>(Mn + 4);
      n2 = *reinterpret_cast<const float4*>(Mn + 8);
      n3 = *reinterpret_cast<const float4*>(Mn + 12);
    }
    float s01 = alpha * c0.x + swz<1>(alpha) * c0.y;
    float s23 = swz<2>(alpha) * c0.z + swz<3>(alpha) * c0.w;
    float s45 = swz<4>(alpha) * c1.x + swz<5>(alpha) * c1.y;
    float s67 = swz<6>(alpha) * c1.z + swz<7>(alpha) * c1.w;
    float s89 = swz<8>(alpha) * c2.x + swz<9>(alpha) * c2.y;
    float sab = swz<10>(alpha) * c2.z + swz<11>(alpha) * c2.w;
    float scd = swz<12>(alpha) * c3.x + swz<13>(alpha) * c3.y;
    float sef = swz<14>(alpha) * c3.z + swz<15>(alpha) * c3.w;
    alpha = ((s01 + s23) + (s45 + s67)) + ((s89 + sab) + (scd + sef));

    if ((k & 3) == 3) {  // renorm every 4 chunks (growth <= 9^4, safe)
      float m = alpha;
      m = fmaxf(m, swz<1>(m));
      m = fmaxf(m, swz<2>(m));
      m = fmaxf(m, swz<4>(m));
      m = fmaxf(m, swz<8>(m));
      float inv = 1.f / m;
      alpha *= inv;
      C += __logf(m);
    }
    if (k + 1 < NCHUNK) { c0 = n0; c1 = n1; c2 = n2; c3 = n3; }
  }

  float s = alpha;
  s += swz<1>(s);
  s += swz<2>(s);
  s += swz<4>(s);
  s += swz<8>(s);
  float result = extra + C + __logf(s) - emit0;

  if (lane == 0) partials[b] = result;
  __threadfence();
  unsigned old = 0;
  if (lane == 0) old = atomicAdd(counter, 1u);
  old = __shfl(old, 0, 64);
  if (old == BB - 1) {  // last block: deterministic fixed-order reduce
    __threadfence();
    float v = partials[lane];
    v += __shfl_xor(v, 1, 64);
    v += __shfl_xor(v, 2, 64);
    v += __shfl_xor(v, 4, 64);
    v += __shfl_xor(v, 8, 64);
    v += __shfl_xor(v, 16, 64);
    v += __shfl_xor(v, 32, 64);
    if (lane == 0) {
      out_val[0] = v;
      *counter = 0u;
    }
  }
}

extern "C" void kernel_launch(void* const* d_in, const int* in_sizes, int n_in,
                              void* d_out, int out_size, void* d_ws,
                              size_t ws_size, hipStream_t stream) {
  const float* inputs = (const float*)d_in[0];
  const int* targets = (const int*)d_in[1];
  const int* seqlen = (const int*)d_in[2];
  const float* W = (const float*)d_in[4];
  const float* bias = (const float*)d_in[5];
  const float* trans = (const float*)d_in[6];
  float* out = (float*)d_out;

  float* mats = (float*)d_ws;                        // 64*32*256 f = 2 MB
  float* scales = mats + (size_t)BB * NCHUNK * 256;  // 2048 f
  float* numblk = scales + (size_t)BB * NCHUNK;      // 512 f
  float* partials = numblk + 512;                    // 64 f
  unsigned* counter = (unsigned*)(partials + BB);    // 1 u32

  fused_kernel<<<512, 256, 0, stream>>>(inputs, W, bias, targets, seqlen,
                                        trans, out + 1, mats, scales, numblk,
                                        counter);
  crf_combine_kernel<<<BB, 64, 0, stream>>>(out + 1, targets, mats, scales,
                                            numblk, partials, counter, out);
}

// Round 7
// 55.475 us; speedup vs baseline: 3.4466x; 3.4466x over previous
//
#include <hip/hip_runtime.h>
#include <hip/hip_bf16.h>
#include <math.h>

#define BB 64
#define SS 512
#define DD 1024
#define LL 9
#define NCHUNK 32
#define CLEN 16
#define WSTR (DD + 4)  // padded LDS row stride: read conflicts <= 2-way (free)

#define DPP_ADD(v, ctrl)                                                     \
  v += __int_as_float(__builtin_amdgcn_update_dpp(                           \
      0, __float_as_int(v), ctrl, 0xF, 0xF, false))

template <int R>
__device__ inline float swz(float x) {
  return __int_as_float(
      __builtin_amdgcn_ds_swizzle(__float_as_int(x), (R << 10) | 0x1F));
}

// ---------------- GEMM: logits[row][l] = sum_k in[row][k]*W[k][l] + b[l]
// 1024 blocks x 256 threads = 4 blocks/CU (LDS 37KB), 16 waves/CU.
// Wave = 8 rows: p = lane&15 k-splits (256B slices), sub = lane>>4 picks
// row, q=0..1 second row quad. ~90 VGPR -> no spill. Global a[] loads
// pipelined 1 iter ahead. W staged dest-major (LDS writes linear,
// conflict-free; global reads strided but L2-hot).
__global__ __launch_bounds__(256) void gemm_kernel(
    const float* __restrict__ in, const float* __restrict__ W,
    const float* __restrict__ bias, float* __restrict__ out) {
  __shared__ float Wt[LL * WSTR];  // 37 KB
  int tid = threadIdx.x;
  for (int idx = tid; idx < LL * DD; idx += 256) {
    int l = idx >> 10, k = idx & (DD - 1);
    Wt[l * WSTR + k] = W[k * LL + l];
  }
  __syncthreads();

  int lane = tid & 63;
  int wave = tid >> 6;
  int p = lane & 15;
  int sub = lane >> 4;

  int r0 = blockIdx.x * 32 + wave * 8 + sub;  // rows r0, r0+4
  const float* x0 = in + (size_t)r0 * DD + p * 4;

  float acc[2][LL];
#pragma unroll
  for (int q = 0; q < 2; ++q)
#pragma unroll
    for (int l = 0; l < LL; ++l) acc[q][l] = 0.f;

  float4 a[2], an[2];
  a[0] = *reinterpret_cast<const float4*>(x0);
  a[1] = *reinterpret_cast<const float4*>(x0 + 4 * DD);

  for (int it = 0; it < 16; ++it) {
    if (it < 15) {
      an[0] = *reinterpret_cast<const float4*>(x0 + (it + 1) * 64);
      an[1] = *reinterpret_cast<const float4*>(x0 + 4 * DD + (it + 1) * 64);
    }
    int k0 = it * 64 + p * 4;
#pragma unroll
    for (int l = 0; l < LL; ++l) {
      float4 w4 = *reinterpret_cast<const float4*>(&Wt[l * WSTR + k0]);
      acc[0][l] += a[0].x * w4.x + a[0].y * w4.y + a[0].z * w4.z +
                   a[0].w * w4.w;
      acc[1][l] += a[1].x * w4.x + a[1].y * w4.y + a[1].z * w4.z +
                   a[1].w * w4.w;
    }
    if (it < 15) {
      a[0] = an[0];
      a[1] = an[1];
    }
  }

#pragma unroll
  for (int q = 0; q < 2; ++q)
#pragma unroll
    for (int l = 0; l < LL; ++l) {
      DPP_ADD(acc[q][l], 0x111);
      DPP_ADD(acc[q][l], 0x112);
      DPP_ADD(acc[q][l], 0x114);
      DPP_ADD(acc[q][l], 0x118);
    }
  if (p == 15) {
#pragma unroll
    for (int q = 0; q < 2; ++q)
#pragma unroll
      for (int l = 0; l < LL; ++l)
        out[(size_t)(r0 + q * 4) * LL + l] = acc[q][l] + bias[l];
  }
}

// ---------------- Phase 1: per-(batch,chunk) 16-step transfer matrix +
// per-chunk numerator partial. Lane j holds ROW j of T. Mats stored
// pre-permuted: T[i][c] -> offset c*16 + (i^c). Block 0 zeroes the
// finisher counter (combine runs after, stream-ordered).
__global__ __launch_bounds__(64) void crf_chunk_kernel(
    const float* __restrict__ logits, const int* __restrict__ targets,
    const int* __restrict__ seqlen, const float* __restrict__ trans,
    float* __restrict__ mats, float* __restrict__ scales,
    float* __restrict__ numpart, unsigned* __restrict__ counter) {
  if (blockIdx.x == 0 && threadIdx.x == 0) *counter = 0u;

  int lane = threadIdx.x;
  int j = lane & 15;
  int gid = blockIdx.x * 4 + (lane >> 4);
  int b = gid >> 5;
  int k = gid & 31;
  int len = seqlen[b];

  float Mx[81];
#pragma unroll
  for (int i = 0; i < 81; ++i) Mx[i] = __expf(trans[i]);

  float T[LL];
#pragma unroll
  for (int c = 0; c < LL; ++c) T[c] = (j == c) ? 1.f : 0.f;
  float Cl = 0.f;

  const float* lb = logits + (size_t)b * SS * LL;
  const int* tb = targets + (size_t)b * SS;
  int t0 = k * CLEN + 1;
  int tend = (t0 + CLEN < SS) ? (t0 + CLEN) : SS;

  float e[LL];
#pragma unroll
  for (int c = 0; c < LL; ++c) e[c] = lb[t0 * LL + c];

  for (int t = t0; t < tend; ++t) {
    float Ex[LL];
#pragma unroll
    for (int c = 0; c < LL; ++c) Ex[c] = __expf(e[c]);
    if (t + 1 < tend) {
#pragma unroll
      for (int c = 0; c < LL; ++c) e[c] = lb[(t + 1) * LL + c];
    }
    bool active = (t < len);
    float nT[LL];
#pragma unroll
    for (int c = 0; c < LL; ++c) {
      float s = 0.f;
#pragma unroll
      for (int m = 0; m < LL; ++m) s += T[m] * Mx[m * LL + c];
      nT[c] = s * Ex[c];
    }
#pragma unroll
    for (int c = 0; c < LL; ++c) T[c] = active ? nT[c] : T[c];

    if (((t - t0) & 7) == 7) {
      float m = T[0];
#pragma unroll
      for (int c = 1; c < LL; ++c) m = fmaxf(m, T[c]);
      m = fmaxf(m, swz<1>(m));
      m = fmaxf(m, swz<2>(m));
      m = fmaxf(m, swz<4>(m));
      m = fmaxf(m, swz<8>(m));
      float inv = 1.f / m;
#pragma unroll
      for (int c = 0; c < LL; ++c) T[c] *= inv;
      Cl += __logf(m);
    }
  }
  {
    float m = T[0];
#pragma unroll
    for (int c = 1; c < LL; ++c) m = fmaxf(m, T[c]);
    m = fmaxf(m, swz<1>(m));
    m = fmaxf(m, swz<2>(m));
    m = fmaxf(m, swz<4>(m));
    m = fmaxf(m, swz<8>(m));
    float inv = 1.f / m;
#pragma unroll
    for (int c = 0; c < LL; ++c) T[c] *= inv;
    Cl += __logf(m);
  }

  float* Mg = mats + (size_t)gid * 256;
#pragma unroll
  for (int c = 0; c < 16; ++c)
    Mg[c * 16 + (j ^ c)] = (c < LL) ? T[c] : 0.f;
  if (j == 0) scales[gid] = Cl;

  // numerator partial for t in [t0, tend): lane j handles t = t0 + j
  int t = t0 + j;
  float np = 0.f;
  if (t < tend && t < len) {
    int tg = tb[t];
    np = lb[t * LL + tg] + trans[tb[t - 1] * LL + tg];
  }
  np += swz<1>(np);
  np += swz<2>(np);
  np += swz<4>(np);
  np += swz<8>(np);
  if (j == 0) numpart[gid] = np;
}

// ---------------- Phase 2: per-batch combine (matvec tree, renorm every 4
// chunks) + deterministic final reduce via last-block finisher.
__global__ __launch_bounds__(64) void crf_combine_kernel(
    const float* __restrict__ logits, const int* __restrict__ targets,
    const float* __restrict__ mats, const float* __restrict__ scales,
    const float* __restrict__ numpart, float* __restrict__ partials,
    unsigned* __restrict__ counter, float* __restrict__ out_val) {
  int lane = threadIdx.x;
  int j = lane & 15;
  int b = blockIdx.x;
  const float* lb = logits + (size_t)b * SS * LL;
  const float* Mb = mats + (size_t)b * NCHUNK * 256;

  // sum of chunk scales minus numerator partials (fixed order)
  float extra = (lane < NCHUNK) ? scales[b * NCHUNK + lane]
                                : -numpart[b * NCHUNK + (lane - 32)];
  extra += __shfl_xor(extra, 1, 64);
  extra += __shfl_xor(extra, 2, 64);
  extra += __shfl_xor(extra, 4, 64);
  extra += __shfl_xor(extra, 8, 64);
  extra += __shfl_xor(extra, 16, 64);
  extra += __shfl_xor(extra, 32, 64);
  float emit0 = lb[targets[(size_t)b * SS]];  // t=0 numerator term

  float alpha = (j < LL) ? __expf(lb[j]) : 0.f;
  float C = 0.f;

  float4 c0 = *reinterpret_cast<const float4*>(Mb + j * 16 + 0);
  float4 c1 = *reinterpret_cast<const float4*>(Mb + j * 16 + 4);
  float4 c2 = *reinterpret_cast<const float4*>(Mb + j * 16 + 8);
  float4 c3 = *reinterpret_cast<const float4*>(Mb + j * 16 + 12);

  for (int k = 0; k < NCHUNK; ++k) {
    float4 n0, n1, n2, n3;
    if (k + 1 < NCHUNK) {
      const float* Mn = Mb + (size_t)(k + 1) * 256 + j * 16;
      n0 = *reinterpret_cast<const float4*>(Mn + 0);
      n1 = *reinterpret_cast<const float4*>(Mn + 4);
      n2 = *reinterpret_cast<const float4*>(Mn + 8);
      n3 = *reinterpret_cast<const float4*>(Mn + 12);
    }
    float s01 = alpha * c0.x + swz<1>(alpha) * c0.y;
    float s23 = swz<2>(alpha) * c0.z + swz<3>(alpha) * c0.w;
    float s45 = swz<4>(alpha) * c1.x + swz<5>(alpha) * c1.y;
    float s67 = swz<6>(alpha) * c1.z + swz<7>(alpha) * c1.w;
    float s89 = swz<8>(alpha) * c2.x + swz<9>(alpha) * c2.y;
    float sab = swz<10>(alpha) * c2.z + swz<11>(alpha) * c2.w;
    float scd = swz<12>(alpha) * c3.x + swz<13>(alpha) * c3.y;
    float sef = swz<14>(alpha) * c3.z + swz<15>(alpha) * c3.w;
    alpha = ((s01 + s23) + (s45 + s67)) + ((s89 + sab) + (scd + sef));

    if ((k & 3) == 3) {  // renorm every 4 chunks (growth <= 9^4, safe)
      float m = alpha;
      m = fmaxf(m, swz<1>(m));
      m = fmaxf(m, swz<2>(m));
      m = fmaxf(m, swz<4>(m));
      m = fmaxf(m, swz<8>(m));
      float inv = 1.f / m;
      alpha *= inv;
      C += __logf(m);
    }
    if (k + 1 < NCHUNK) { c0 = n0; c1 = n1; c2 = n2; c3 = n3; }
  }

  float s = alpha;
  s += swz<1>(s);
  s += swz<2>(s);
  s += swz<4>(s);
  s += swz<8>(s);
  float result = extra + C + __logf(s) - emit0;

  if (lane == 0) partials[b] = result;
  __threadfence();
  unsigned old = 0;
  if (lane == 0) old = atomicAdd(counter, 1u);
  old = __shfl(old, 0, 64);
  if (old == BB - 1) {  // last block: deterministic fixed-order reduce
    __threadfence();
    float v = partials[lane];
    v += __shfl_xor(v, 1, 64);
    v += __shfl_xor(v, 2, 64);
    v += __shfl_xor(v, 4, 64);
    v += __shfl_xor(v, 8, 64);
    v += __shfl_xor(v, 16, 64);
    v += __shfl_xor(v, 32, 64);
    if (lane == 0) {
      out_val[0] = v;
      *counter = 0u;
    }
  }
}

extern "C" void kernel_launch(void* const* d_in, const int* in_sizes, int n_in,
                              void* d_out, int out_size, void* d_ws,
                              size_t ws_size, hipStream_t stream) {
  const float* inputs = (const float*)d_in[0];
  const int* targets = (const int*)d_in[1];
  const int* seqlen = (const int*)d_in[2];
  const float* W = (const float*)d_in[4];
  const float* bias = (const float*)d_in[5];
  const float* trans = (const float*)d_in[6];
  float* out = (float*)d_out;

  float* mats = (float*)d_ws;                        // 64*32*256 f = 2 MB
  float* scales = mats + (size_t)BB * NCHUNK * 256;  // 2048 f
  float* numpart = scales + (size_t)BB * NCHUNK;     // 2048 f
  float* partials = numpart + (size_t)BB * NCHUNK;   // 64 f
  unsigned* counter = (unsigned*)(partials + BB);    // 1 u32

  gemm_kernel<<<1024, 256, 0, stream>>>(inputs, W, bias, out + 1);
  crf_chunk_kernel<<<BB * NCHUNK / 4, 64, 0, stream>>>(
      out + 1, targets, seqlen, trans, mats, scales, numpart, counter);
  crf_combine_kernel<<<BB, 64, 0, stream>>>(out + 1, targets, mats, scales,
                                            numpart, partials, counter, out);
}